// Round 2
// baseline (264.727 us; speedup 1.0000x reference)
//
#include <hip/hip_runtime.h>
#include <hip/hip_bf16.h>

// Problem constants
#define B_ 4
#define S_ 2048
#define D_ 128
#define H_ 8

typedef __attribute__((ext_vector_type(8))) short bf16x8;
typedef __attribute__((ext_vector_type(4))) float f32x4;

__device__ __forceinline__ short f2bf(float f) {
  union { float f; unsigned u; } v; v.f = f;
  unsigned u = v.u;
  unsigned r = (u + 0x7FFFu + ((u >> 16) & 1u)) >> 16;
  return (short)r;
}

// pack 4 fp32 -> 4 bf16 (RNE) as short4
__device__ __forceinline__ short4 pack4(f32x4 p) {
  union { __hip_bfloat162 h2[2]; short4 s4; } u;
  u.h2[0] = __float22bfloat162_rn(make_float2(p[0], p[1]));
  u.h2[1] = __float22bfloat162_rn(make_float2(p[2], p[3]));
  return u.s4;
}

// async global->LDS DMA, 16 B per lane. LDS dest = wave-uniform base + lane*16.
__device__ __forceinline__ void dma16(const short* g, short* l) {
  __builtin_amdgcn_global_load_lds(
      (const __attribute__((address_space(1))) unsigned int*)g,
      (__attribute__((address_space(3))) unsigned int*)l, 16, 0, 0);
}

// Fused prep: blocks [0,3072) = fp32->bf16 convert of q,k,v (float4 chunks);
// blocks [3072,3168) = transpose+convert W (128,1024) fp32 -> Wt (1024,128) bf16.
// The two halves are independent; fusing saves one launch gap.
__global__ __launch_bounds__(256) void prep(
    const float* __restrict__ a, const float* __restrict__ b, const float* __restrict__ c,
    short* __restrict__ oa, short* __restrict__ ob, short* __restrict__ oc,
    const float* __restrict__ WQ, const float* __restrict__ WK, const float* __restrict__ WV,
    short* __restrict__ TQ, short* __restrict__ TK, short* __restrict__ TV) {
  __shared__ float tile[64][65];
  if (blockIdx.x < 3072) {
    int i = blockIdx.x * 256 + threadIdx.x;
    int which = i >> 18;
    int j = i & 262143;
    const float* in = (which == 0) ? a : (which == 1) ? b : c;
    short* out = (which == 0) ? oa : (which == 1) ? ob : oc;
    float4 v = ((const float4*)in)[j];
    short4 o = make_short4(f2bf(v.x), f2bf(v.y), f2bf(v.z), f2bf(v.w));
    ((short4*)out)[j] = o;
  } else {
    int bid = blockIdx.x - 3072;
    int bw = bid >> 5;
    int tl = bid & 31;
    int n0 = (tl & 15) * 64, k0 = (tl >> 4) * 64;
    const float* W = (bw == 0) ? WQ : (bw == 1) ? WK : WV;
    short* Wt = (bw == 0) ? TQ : (bw == 1) ? TK : TV;
#pragma unroll
    for (int i = 0; i < 16; ++i) {
      int cix = threadIdx.x + 256 * i;
      int rr = cix >> 6, cc = cix & 63;
      tile[rr][cc] = W[(k0 + rr) * 1024 + n0 + cc];
    }
    __syncthreads();
#pragma unroll
    for (int i = 0; i < 16; ++i) {
      int cix = threadIdx.x + 256 * i;
      int rr = cix >> 6, cc = cix & 63;
      Wt[(n0 + rr) * 128 + k0 + cc] = f2bf(tile[cc][rr]);
    }
  }
}

// ---------------------------------------------------------------------------
// Tiled projection: block = 128(M:s) x 128(N:h*128+d) output tile, K=128 in one
// shot. Operands staged to LDS in MFMA-fragment order (1 KB lane-contiguous
// frags -> conflict-free ds_read_b128) via global_load_lds width-16.
// ---------------------------------------------------------------------------
template <int WA>
__device__ __forceinline__ void proj_tile(const short* __restrict__ X,
                                          const short* __restrict__ Wt,
                                          const float* __restrict__ bias,
                                          short* __restrict__ out,
                                          int mtile, int ntile,
                                          short* sA, short* sB) {
  int tid = threadIdx.x;
  int lane = tid & 63, w = tid >> 6;
  int l15 = lane & 15, l4 = lane >> 4;
  int m0 = mtile * 128, n0 = ntile * 128;

#pragma unroll
  for (int j = 0; j < 8; ++j) {
    int f = w * 8 + j;
    const short* src = X + (m0 + (f >> 2) * 16 + l15) * 128 + (f & 3) * 32 + l4 * 8;
    dma16(src, sA + f * 512);
  }
#pragma unroll
  for (int j = 0; j < 8; ++j) {
    int f = w * 8 + j;
    const short* src = Wt + (n0 + (f >> 2) * 16 + l15) * 128 + (f & 3) * 32 + l4 * 8;
    dma16(src, sB + f * 512);
  }
  __syncthreads();  // drains vmcnt (DMA complete)

  int wr = w >> 1, wc = w & 1;  // wave -> 64x64 quadrant
  f32x4 acc[4][4];
#pragma unroll
  for (int mi = 0; mi < 4; ++mi)
#pragma unroll
    for (int ni = 0; ni < 4; ++ni) acc[mi][ni] = (f32x4){0.f, 0.f, 0.f, 0.f};

#pragma unroll
  for (int mi = 0; mi < 4; ++mi) {
    bf16x8 a[4];
#pragma unroll
    for (int st = 0; st < 4; ++st)
      a[st] = *(const bf16x8*)(sA + ((wr * 4 + mi) * 4 + st) * 512 + lane * 8);
#pragma unroll
    for (int ni = 0; ni < 4; ++ni) {
#pragma unroll
      for (int st = 0; st < 4; ++st) {
        bf16x8 b = *(const bf16x8*)(sB + ((wc * 4 + ni) * 4 + st) * 512 + lane * 8);
        if (WA)
          acc[mi][ni] = __builtin_amdgcn_mfma_f32_16x16x32_bf16(b, a[st], acc[mi][ni], 0, 0, 0);
        else
          acc[mi][ni] = __builtin_amdgcn_mfma_f32_16x16x32_bf16(a[st], b, acc[mi][ni], 0, 0, 0);
      }
    }
  }

  if (WA) {
    // C rows = n (l4*4+r), cols = s (l15). h = ntile.
#pragma unroll
    for (int mi = 0; mi < 4; ++mi) {
      int sg = m0 + wr * 64 + mi * 16 + l15;
      int bb = sg >> 11, s = sg & 2047;
      short* orow = out + ((size_t)(bb * H_ + ntile) * S_ + s) * D_;
#pragma unroll
      for (int ni = 0; ni < 4; ++ni) {
        int d0 = wc * 64 + ni * 16 + l4 * 4;
        float4 bv = *(const float4*)(bias + n0 + d0);
        f32x4 t = acc[mi][ni];
        t[0] += bv.x; t[1] += bv.y; t[2] += bv.z; t[3] += bv.w;
        *(short4*)(orow + d0) = pack4(t);
      }
    }
  } else {
    // C rows = s (l4*4+r), cols = n (l15). Transposed store [b,h,d,s].
#pragma unroll
    for (int ni = 0; ni < 4; ++ni) {
      int d = wc * 64 + ni * 16 + l15;
      float bv = bias[n0 + d];
#pragma unroll
      for (int mi = 0; mi < 4; ++mi) {
        int sg0 = m0 + wr * 64 + mi * 16 + l4 * 4;
        int bb = sg0 >> 11, s0 = sg0 & 2047;
        f32x4 t = acc[mi][ni];
        t[0] += bv; t[1] += bv; t[2] += bv; t[3] += bv;
        *(short4*)(out + ((size_t)(bb * H_ + ntile) * D_ + d) * S_ + s0) = pack4(t);
      }
    }
  }
}

// 1536 blocks = 3 projs x 64 m-tiles x 8 n-tiles, n fastest, XCD chunk-swizzled.
__global__ __launch_bounds__(256, 2) void proj3(
    const short* __restrict__ xq, const short* __restrict__ xk, const short* __restrict__ xv,
    const short* __restrict__ wtq, const short* __restrict__ wtk, const short* __restrict__ wtv,
    const float* __restrict__ bQ, const float* __restrict__ bK, const float* __restrict__ bV,
    short* __restrict__ Qp, short* __restrict__ Kp, short* __restrict__ Vt) {
  __shared__ short sA[16384], sB[16384];
  int work = (blockIdx.x & 7) * 192 + (blockIdx.x >> 3);
  int which = work >> 9;
  int t = work & 511;
  int mtile = t >> 3, ntile = t & 7;
  if (which == 0)      proj_tile<1>(xq, wtq, bQ, Qp, mtile, ntile, sA, sB);
  else if (which == 1) proj_tile<1>(xk, wtk, bK, Kp, mtile, ntile, sA, sB);
  else                 proj_tile<0>(xv, wtv, bV, Vt, mtile, ntile, sA, sB);
}

// Flash-style attention with |score| softmax, NO max tracking.
// S^T formulation (A=K, B=Q). K double-buffered in LDS (fragment order, DMA).
// V-fragments are read DIRECTLY from global/L2: Vt[b,h,d,s] makes each B-frag a
// coalesced 16 B/lane load that reproduces the old LDS lane<->value map exactly.
// This moves ~16 KB/wave-iter off the saturated DS pipe onto the idle L2 pipe.
#define BN 64
#define PSTR 72  // P row stride (shorts)

#define ATTN_ITER(KB, KN, IT)                                                  \
  {                                                                            \
    const int kb_ = (IT) * BN;                                                 \
    if ((IT) + 1 < S_ / BN) {                                                  \
      int kt_ = ((IT) + 1) * BN;                                               \
      const short* kgs = kg + kt_ * D_;                                        \
      short* kl = (KN) + (w * 4) * 512;                                        \
      dma16(kgs, kl);                                                          \
      dma16(kgs + 32, kl + 512);                                               \
      dma16(kgs + 64, kl + 1024);                                              \
      dma16(kgs + 96, kl + 1536);                                              \
    }                                                                          \
    /* V-frag prefetch, first half: hides L2 latency under QK MFMAs */         \
    bf16x8 bv[16];                                                             \
    _Pragma("unroll") for (int tt = 0; tt < 4; ++tt) {                         \
      bv[tt * 2]     = *(const bf16x8*)(vp + tt * 16 * S_ + kb_);              \
      bv[tt * 2 + 1] = *(const bf16x8*)(vp + tt * 16 * S_ + kb_ + 32);         \
    }                                                                          \
    /* S^T = K Q^T for both q-groups; K-frags read once, used twice */         \
    f32x4 s0[4], s1[4];                                                        \
    __builtin_amdgcn_s_setprio(1);                                             \
    _Pragma("unroll") for (int mt = 0; mt < 4; ++mt) {                         \
      s0[mt] = (f32x4){0.f, 0.f, 0.f, 0.f};                                    \
      s1[mt] = (f32x4){0.f, 0.f, 0.f, 0.f};                                    \
      _Pragma("unroll") for (int st = 0; st < 4; ++st) {                       \
        bf16x8 bk = *(const bf16x8*)((KB) + (mt * 4 + st) * 512 + lane * 8);   \
        s0[mt] = __builtin_amdgcn_mfma_f32_16x16x32_bf16(bk, aq[0][st], s0[mt], 0, 0, 0); \
        s1[mt] = __builtin_amdgcn_mfma_f32_16x16x32_bf16(bk, aq[1][st], s1[mt], 0, 0, 0); \
      }                                                                        \
    }                                                                          \
    __builtin_amdgcn_s_setprio(0);                                             \
    /* V-frag prefetch, second half: hides under softmax */                    \
    _Pragma("unroll") for (int tt = 4; tt < 8; ++tt) {                         \
      bv[tt * 2]     = *(const bf16x8*)(vp + tt * 16 * S_ + kb_);              \
      bv[tt * 2 + 1] = *(const bf16x8*)(vp + tt * 16 * S_ + kb_ + 32);         \
    }                                                                          \
    /* softmax g0: p = exp2(|s|*SC2); P via LDS round-trip (layout convert) */ \
    bf16x8 ap0[2], ap1[2];                                                     \
    _Pragma("unroll") for (int mt = 0; mt < 4; ++mt) {                         \
      _Pragma("unroll") for (int r = 0; r < 4; ++r) {                          \
        float p = __builtin_amdgcn_exp2f(fabsf(s0[mt][r]) * SC2);              \
        ls0 += p;                                                              \
        s0[mt][r] = p;                                                         \
      }                                                                        \
      *(short4*)(pw + l15 * PSTR + mt * 16 + l4 * 4) = pack4(s0[mt]);          \
    }                                                                          \
    ap0[0] = *(const bf16x8*)(pw + l15 * PSTR + l4 * 8);                       \
    ap0[1] = *(const bf16x8*)(pw + l15 * PSTR + 32 + l4 * 8);                  \
    /* softmax g1 (same per-wave P region; DS ops are in-order) */             \
    _Pragma("unroll") for (int mt = 0; mt < 4; ++mt) {                         \
      _Pragma("unroll") for (int r = 0; r < 4; ++r) {                          \
        float p = __builtin_amdgcn_exp2f(fabsf(s1[mt][r]) * SC2);              \
        ls1 += p;                                                              \
        s1[mt][r] = p;                                                         \
      }                                                                        \
      *(short4*)(pw + l15 * PSTR + mt * 16 + l4 * 4) = pack4(s1[mt]);          \
    }                                                                          \
    ap1[0] = *(const bf16x8*)(pw + l15 * PSTR + l4 * 8);                       \
    ap1[1] = *(const bf16x8*)(pw + l15 * PSTR + 32 + l4 * 8);                  \
    /* O += P V ; register V-frags shared by both q-groups */                  \
    __builtin_amdgcn_s_setprio(1);                                             \
    _Pragma("unroll") for (int t = 0; t < 8; ++t) {                            \
      _Pragma("unroll") for (int kst = 0; kst < 2; ++kst) {                    \
        o0[t] = __builtin_amdgcn_mfma_f32_16x16x32_bf16(ap0[kst], bv[t * 2 + kst], o0[t], 0, 0, 0); \
        o1[t] = __builtin_amdgcn_mfma_f32_16x16x32_bf16(ap1[kst], bv[t * 2 + kst], o1[t], 0, 0, 0); \
      }                                                                        \
    }                                                                          \
    __builtin_amdgcn_s_setprio(0);                                             \
    __syncthreads(); /* drains vmcnt (next-tile K DMA) + guards K buffer */    \
  }

__global__ __launch_bounds__(256, 2) void attn(const short* __restrict__ Qp,
                                               const short* __restrict__ Kp,
                                               const short* __restrict__ Vt,
                                               float* __restrict__ out) {
  __shared__ short sK0[8192], sK1[8192];  // 16 KB each, fragment-order
  __shared__ short sP[4 * 16 * PSTR];     // per-wave P region

  int tid = threadIdx.x;
  int lane = tid & 63, w = tid >> 6;
  // XCD chunk-swizzle (bijective, 512 blocks): XCD x owns works [x*64,(x+1)*64)
  // -> 4 (b,h) pairs per XCD; K/V working set ~4 MB = one L2.
  int swz = (blockIdx.x & 7) * 64 + (blockIdx.x >> 3);
  int qt = swz & 15; // 16 q-tiles of 128
  int bh = swz >> 4; // 0..31
  int q0 = qt * 128;
  int l15 = lane & 15, l4 = lane >> 4;

  const short* Qbase = Qp + (size_t)bh * S_ * D_;
  const short* Kbase = Kp + (size_t)bh * S_ * D_;
  const short* Vbase = Vt + (size_t)bh * D_ * S_;

  // K DMA source address (fragment-order image)
  const short* kg = Kbase + (w * 16 + l15) * D_ + l4 * 8;
  // V fragment base: lane (l15,l4) reads Vt[row t*16+l15][key kb+kst*32+l4*8..+8]
  const short* vp = Vbase + l15 * S_ + l4 * 8;

  // stage K tile 0 into buffer 0
  {
    short* kl = sK0 + (w * 4) * 512;
    dma16(kg, kl);
    dma16(kg + 32, kl + 512);
    dma16(kg + 64, kl + 1024);
    dma16(kg + 96, kl + 1536);
  }

  // Q B-fragments for two 16-q groups (q = q0 + w*32 + g*16 + l15)
  bf16x8 aq[2][4];
#pragma unroll
  for (int g = 0; g < 2; ++g)
#pragma unroll
    for (int st = 0; st < 4; ++st)
      aq[g][st] = *(const bf16x8*)(Qbase + (q0 + w * 32 + g * 16 + l15) * D_ + l4 * 8 + 32 * st);

  f32x4 o0[8], o1[8];
#pragma unroll
  for (int t = 0; t < 8; ++t) {
    o0[t] = (f32x4){0.f, 0.f, 0.f, 0.f};
    o1[t] = (f32x4){0.f, 0.f, 0.f, 0.f};
  }
  float ls0 = 0.f, ls1 = 0.f;

  const float SC2 = 0.127530637f; // log2(e)/sqrt(128)
  short* pw = sP + w * 16 * PSTR;

  __syncthreads(); // tile 0 K DMA complete

  for (int it = 0; it < S_ / BN; it += 2) {
    ATTN_ITER(sK0, sK1, it);
    ATTN_ITER(sK1, sK0, it + 1);
  }

  // final softmax denominators: per-lane partial sums -> quad reduce
  ls0 += __shfl_xor(ls0, 16);
  ls0 += __shfl_xor(ls0, 32);
  ls1 += __shfl_xor(ls1, 16);
  ls1 += __shfl_xor(ls1, 32);
  float inv0[4], inv1[4];
#pragma unroll
  for (int r = 0; r < 4; ++r) {
    inv0[r] = 1.f / __shfl(ls0, l4 * 4 + r);
    inv1[r] = 1.f / __shfl(ls1, l4 * 4 + r);
  }

  // epilogue: out[b, q, h*128 + dv] fp32
  int bb = bh >> 3, h = bh & 7;
#pragma unroll
  for (int t = 0; t < 8; ++t) {
#pragma unroll
    for (int r = 0; r < 4; ++r) {
      int qA = q0 + w * 32 + l4 * 4 + r;
      int qB = qA + 16;
      out[((size_t)(bb * S_ + qA)) * (H_ * D_) + h * D_ + t * 16 + l15] = o0[t][r] * inv0[r];
      out[((size_t)(bb * S_ + qB)) * (H_ * D_) + h * D_ + t * 16 + l15] = o1[t][r] * inv1[r];
    }
  }
}

extern "C" void kernel_launch(void* const* d_in, const int* in_sizes, int n_in,
                              void* d_out, int out_size, void* d_ws, size_t ws_size,
                              hipStream_t stream) {
  (void)in_sizes; (void)n_in; (void)out_size; (void)ws_size;
  const float* q  = (const float*)d_in[0];
  const float* k  = (const float*)d_in[1];
  const float* v  = (const float*)d_in[2];
  const float* WQ = (const float*)d_in[3];
  const float* bQ = (const float*)d_in[4];
  const float* WK = (const float*)d_in[5];
  const float* bK = (const float*)d_in[6];
  const float* WV = (const float*)d_in[7];
  const float* bV = (const float*)d_in[8];

  const int NX = B_ * S_ * D_;      // 1048576 elems per input tensor
  const int NW = D_ * H_ * D_;      // 131072 per weight
  const int NP = B_ * H_ * S_ * D_; // 8388608 per projected tensor

  short* ws  = (short*)d_ws;
  short* xq  = ws;
  short* xk  = xq + NX;
  short* xv  = xk + NX;
  short* wtq = xv + NX;
  short* wtk = wtq + NW;
  short* wtv = wtk + NW;
  short* Qp  = wtv + NW;
  short* Kp  = Qp + NP;
  short* Vt  = Kp + NP;

  prep<<<3168, 256, 0, stream>>>(q, k, v, xq, xk, xv, WQ, WK, WV, wtq, wtk, wtv);

  proj3<<<1536, 256, 0, stream>>>(xq, xk, xv, wtq, wtk, wtv, bQ, bK, bV, Qp, Kp, Vt);

  attn<<<512, 256, 0, stream>>>(Qp, Kp, Vt, (float*)d_out);
}

// Round 4
// 193.184 us; speedup vs baseline: 1.3703x; 1.3703x over previous
//
#include <hip/hip_runtime.h>
#include <hip/hip_bf16.h>

// Problem constants
#define B_ 4
#define S_ 2048
#define D_ 128
#define H_ 8

typedef __attribute__((ext_vector_type(8))) short bf16x8;
typedef __attribute__((ext_vector_type(4))) float f32x4;

__device__ __forceinline__ short f2bf(float f) {
  union { float f; unsigned u; } v; v.f = f;
  unsigned u = v.u;
  unsigned r = (u + 0x7FFFu + ((u >> 16) & 1u)) >> 16;
  return (short)r;
}

// pack 4 fp32 -> 4 bf16 (RNE) as short4
__device__ __forceinline__ short4 pack4(f32x4 p) {
  union { __hip_bfloat162 h2[2]; short4 s4; } u;
  u.h2[0] = __float22bfloat162_rn(make_float2(p[0], p[1]));
  u.h2[1] = __float22bfloat162_rn(make_float2(p[2], p[3]));
  return u.s4;
}

// async global->LDS DMA, 16 B per lane. LDS dest = wave-uniform base + lane*16.
__device__ __forceinline__ void dma16(const short* g, short* l) {
  __builtin_amdgcn_global_load_lds(
      (const __attribute__((address_space(1))) unsigned int*)g,
      (__attribute__((address_space(3))) unsigned int*)l, 16, 0, 0);
}

// Fused prep: blocks [0,3072) = fp32->bf16 convert of q,k,v (float4 chunks);
// blocks [3072,3168) = transpose+convert W (128,1024) fp32 -> Wt (1024,128) bf16.
__global__ __launch_bounds__(256) void prep(
    const float* __restrict__ a, const float* __restrict__ b, const float* __restrict__ c,
    short* __restrict__ oa, short* __restrict__ ob, short* __restrict__ oc,
    const float* __restrict__ WQ, const float* __restrict__ WK, const float* __restrict__ WV,
    short* __restrict__ TQ, short* __restrict__ TK, short* __restrict__ TV) {
  __shared__ float tile[64][65];
  if (blockIdx.x < 3072) {
    int i = blockIdx.x * 256 + threadIdx.x;
    int which = i >> 18;
    int j = i & 262143;
    const float* in = (which == 0) ? a : (which == 1) ? b : c;
    short* out = (which == 0) ? oa : (which == 1) ? ob : oc;
    float4 v = ((const float4*)in)[j];
    short4 o = make_short4(f2bf(v.x), f2bf(v.y), f2bf(v.z), f2bf(v.w));
    ((short4*)out)[j] = o;
  } else {
    int bid = blockIdx.x - 3072;
    int bw = bid >> 5;
    int tl = bid & 31;
    int n0 = (tl & 15) * 64, k0 = (tl >> 4) * 64;
    const float* W = (bw == 0) ? WQ : (bw == 1) ? WK : WV;
    short* Wt = (bw == 0) ? TQ : (bw == 1) ? TK : TV;
#pragma unroll
    for (int i = 0; i < 16; ++i) {
      int cix = threadIdx.x + 256 * i;
      int rr = cix >> 6, cc = cix & 63;
      tile[rr][cc] = W[(k0 + rr) * 1024 + n0 + cc];
    }
    __syncthreads();
#pragma unroll
    for (int i = 0; i < 16; ++i) {
      int cix = threadIdx.x + 256 * i;
      int rr = cix >> 6, cc = cix & 63;
      Wt[(n0 + rr) * 128 + k0 + cc] = f2bf(tile[cc][rr]);
    }
  }
}

// ---------------------------------------------------------------------------
// Tiled projection: block = 128(M:s) x 128(N:h*128+d) output tile, K=128 in one
// shot. Operands staged to LDS in MFMA-fragment order via global_load_lds w=16.
// WA=1 (Q/K): out[b,h,s,d] row-major, short4 stores.
// WA=0 (V):   out = fragment-linear image VF[bh][kb][F][lane][e]:
//   element (key, d):  kb = key>>6, F = (d>>4)*2 + ((key>>5)&1),
//   within-frag short offset = ((key>>3)&3)*128 + (d&15)*8 + (key&7)
//   (lane = l4*16 + l15 with l4=(key>>3)&3, l15=d&15; e=key&7).
//   This is EXACTLY the byte order the attn wave consumes -> each V fragment
//   is a contiguous 1 KB wave-load (16 B/lane).
// ---------------------------------------------------------------------------
template <int WA>
__device__ __forceinline__ void proj_tile(const short* __restrict__ X,
                                          const short* __restrict__ Wt,
                                          const float* __restrict__ bias,
                                          short* __restrict__ out,
                                          int mtile, int ntile,
                                          short* sA, short* sB) {
  int tid = threadIdx.x;
  int lane = tid & 63, w = tid >> 6;
  int l15 = lane & 15, l4 = lane >> 4;
  int m0 = mtile * 128, n0 = ntile * 128;

#pragma unroll
  for (int j = 0; j < 8; ++j) {
    int f = w * 8 + j;
    const short* src = X + (m0 + (f >> 2) * 16 + l15) * 128 + (f & 3) * 32 + l4 * 8;
    dma16(src, sA + f * 512);
  }
#pragma unroll
  for (int j = 0; j < 8; ++j) {
    int f = w * 8 + j;
    const short* src = Wt + (n0 + (f >> 2) * 16 + l15) * 128 + (f & 3) * 32 + l4 * 8;
    dma16(src, sB + f * 512);
  }
  __syncthreads();  // drains vmcnt (DMA complete)

  int wr = w >> 1, wc = w & 1;  // wave -> 64x64 quadrant
  f32x4 acc[4][4];
#pragma unroll
  for (int mi = 0; mi < 4; ++mi)
#pragma unroll
    for (int ni = 0; ni < 4; ++ni) acc[mi][ni] = (f32x4){0.f, 0.f, 0.f, 0.f};

#pragma unroll
  for (int mi = 0; mi < 4; ++mi) {
    bf16x8 a[4];
#pragma unroll
    for (int st = 0; st < 4; ++st)
      a[st] = *(const bf16x8*)(sA + ((wr * 4 + mi) * 4 + st) * 512 + lane * 8);
#pragma unroll
    for (int ni = 0; ni < 4; ++ni) {
#pragma unroll
      for (int st = 0; st < 4; ++st) {
        bf16x8 b = *(const bf16x8*)(sB + ((wc * 4 + ni) * 4 + st) * 512 + lane * 8);
        if (WA)
          acc[mi][ni] = __builtin_amdgcn_mfma_f32_16x16x32_bf16(b, a[st], acc[mi][ni], 0, 0, 0);
        else
          acc[mi][ni] = __builtin_amdgcn_mfma_f32_16x16x32_bf16(a[st], b, acc[mi][ni], 0, 0, 0);
      }
    }
  }

  if (WA) {
    // C rows = n (l4*4+r), cols = s (l15). h = ntile.
#pragma unroll
    for (int mi = 0; mi < 4; ++mi) {
      int sg = m0 + wr * 64 + mi * 16 + l15;
      int bb = sg >> 11, s = sg & 2047;
      short* orow = out + ((size_t)(bb * H_ + ntile) * S_ + s) * D_;
#pragma unroll
      for (int ni = 0; ni < 4; ++ni) {
        int d0 = wc * 64 + ni * 16 + l4 * 4;
        float4 bv = *(const float4*)(bias + n0 + d0);
        f32x4 t = acc[mi][ni];
        t[0] += bv.x; t[1] += bv.y; t[2] += bv.z; t[3] += bv.w;
        *(short4*)(orow + d0) = pack4(t);
      }
    }
  } else {
    // C rows = s/key (l4*4+r), cols = n/d (l15). Fragment-linear store.
    // Lane holds keys s0..s0+3 (s0%8 in {0,4}) for one d -> 4 consecutive e
    // slots -> short4 store at ((s0>>3)&3)*128 + (d&15)*8 + (s0&7).
#pragma unroll
    for (int ni = 0; ni < 4; ++ni) {
      int d = wc * 64 + ni * 16 + l15;
      float bvs = bias[n0 + d];
#pragma unroll
      for (int mi = 0; mi < 4; ++mi) {
        int sg0 = m0 + wr * 64 + mi * 16 + l4 * 4;
        int bb = sg0 >> 11, s0 = sg0 & 2047;
        f32x4 t = acc[mi][ni];
        t[0] += bvs; t[1] += bvs; t[2] += bvs; t[3] += bvs;
        size_t off = (size_t)(bb * H_ + ntile) * (S_ * D_)
                   + (size_t)(s0 >> 6) * 8192
                   + (size_t)((d >> 4) * 2 + ((s0 >> 5) & 1)) * 512
                   + ((s0 >> 3) & 3) * 128 + (d & 15) * 8
                   + (s0 & 7);
        *(short4*)(out + off) = pack4(t);
      }
    }
  }
}

// 1536 blocks = 3 projs x 64 m-tiles x 8 n-tiles, n fastest, XCD chunk-swizzled.
__global__ __launch_bounds__(256, 2) void proj3(
    const short* __restrict__ xq, const short* __restrict__ xk, const short* __restrict__ xv,
    const short* __restrict__ wtq, const short* __restrict__ wtk, const short* __restrict__ wtv,
    const float* __restrict__ bQ, const float* __restrict__ bK, const float* __restrict__ bV,
    short* __restrict__ Qp, short* __restrict__ Kp, short* __restrict__ Vf) {
  __shared__ short sA[16384], sB[16384];
  int work = (blockIdx.x & 7) * 192 + (blockIdx.x >> 3);
  int which = work >> 9;
  int t = work & 511;
  int mtile = t >> 3, ntile = t & 7;
  if (which == 0)      proj_tile<1>(xq, wtq, bQ, Qp, mtile, ntile, sA, sB);
  else if (which == 1) proj_tile<1>(xk, wtk, bK, Kp, mtile, ntile, sA, sB);
  else                 proj_tile<0>(xv, wtv, bV, Vf, mtile, ntile, sA, sB);
}

// Flash-style attention with |score| softmax, NO max tracking.
// S^T formulation (A=K, B=Q). K double-buffered in LDS (fragment order, DMA).
// V read from global/L2 in FRAGMENT-LINEAR layout: each frag = contiguous 1 KB
// wave-load (16 B/lane), issued in two pinned batches covered by QK / softmax.
#define BN 64
#define PSTR 72  // P row stride (shorts)

#define ATTN_ITER(KB, KN, IT)                                                  \
  {                                                                            \
    if ((IT) + 1 < S_ / BN) {                                                  \
      int kt_ = ((IT) + 1) * BN;                                               \
      const short* kgs = kg + kt_ * D_;                                        \
      short* kl = (KN) + (w * 4) * 512;                                        \
      dma16(kgs, kl);                                                          \
      dma16(kgs + 32, kl + 512);                                               \
      dma16(kgs + 64, kl + 1024);                                              \
      dma16(kgs + 96, kl + 1536);                                              \
    }                                                                          \
    /* V-frags 0..7: contiguous 1 KB wave-loads; pinned before QK cluster */   \
    bf16x8 bv[16];                                                             \
    _Pragma("unroll") for (int f = 0; f < 8; ++f)                              \
      bv[f] = *(const bf16x8*)(vfb + (IT) * 8192 + f * 512);                   \
    __builtin_amdgcn_sched_barrier(0);                                         \
    /* S^T = K Q^T for both q-groups; K-frags read once, used twice */         \
    f32x4 s0[4], s1[4];                                                        \
    __builtin_amdgcn_s_setprio(1);                                             \
    _Pragma("unroll") for (int mt = 0; mt < 4; ++mt) {                         \
      s0[mt] = (f32x4){0.f, 0.f, 0.f, 0.f};                                    \
      s1[mt] = (f32x4){0.f, 0.f, 0.f, 0.f};                                    \
      _Pragma("unroll") for (int st = 0; st < 4; ++st) {                       \
        bf16x8 bk = *(const bf16x8*)((KB) + (mt * 4 + st) * 512 + lane * 8);   \
        s0[mt] = __builtin_amdgcn_mfma_f32_16x16x32_bf16(bk, aq[0][st], s0[mt], 0, 0, 0); \
        s1[mt] = __builtin_amdgcn_mfma_f32_16x16x32_bf16(bk, aq[1][st], s1[mt], 0, 0, 0); \
      }                                                                        \
    }                                                                          \
    __builtin_amdgcn_s_setprio(0);                                             \
    /* V-frags 8..15: pinned before softmax (covered by exp2/pack VALU) */     \
    _Pragma("unroll") for (int f = 8; f < 16; ++f)                             \
      bv[f] = *(const bf16x8*)(vfb + (IT) * 8192 + f * 512);                   \
    __builtin_amdgcn_sched_barrier(0);                                         \
    /* softmax g0: p = exp2(|s|*SC2); P via LDS round-trip (layout convert) */ \
    bf16x8 ap0[2], ap1[2];                                                     \
    _Pragma("unroll") for (int mt = 0; mt < 4; ++mt) {                         \
      _Pragma("unroll") for (int r = 0; r < 4; ++r) {                          \
        float p = __builtin_amdgcn_exp2f(fabsf(s0[mt][r]) * SC2);              \
        ls0 += p;                                                              \
        s0[mt][r] = p;                                                         \
      }                                                                        \
      *(short4*)(pw + l15 * PSTR + mt * 16 + l4 * 4) = pack4(s0[mt]);          \
    }                                                                          \
    ap0[0] = *(const bf16x8*)(pw + l15 * PSTR + l4 * 8);                       \
    ap0[1] = *(const bf16x8*)(pw + l15 * PSTR + 32 + l4 * 8);                  \
    /* softmax g1 (same per-wave P region; DS ops are in-order) */             \
    _Pragma("unroll") for (int mt = 0; mt < 4; ++mt) {                         \
      _Pragma("unroll") for (int r = 0; r < 4; ++r) {                          \
        float p = __builtin_amdgcn_exp2f(fabsf(s1[mt][r]) * SC2);              \
        ls1 += p;                                                              \
        s1[mt][r] = p;                                                         \
      }                                                                        \
      *(short4*)(pw + l15 * PSTR + mt * 16 + l4 * 4) = pack4(s1[mt]);          \
    }                                                                          \
    ap1[0] = *(const bf16x8*)(pw + l15 * PSTR + l4 * 8);                       \
    ap1[1] = *(const bf16x8*)(pw + l15 * PSTR + 32 + l4 * 8);                  \
    /* O += P V ; register V-frags shared by both q-groups */                  \
    __builtin_amdgcn_s_setprio(1);                                             \
    _Pragma("unroll") for (int t = 0; t < 8; ++t) {                            \
      _Pragma("unroll") for (int kst = 0; kst < 2; ++kst) {                    \
        o0[t] = __builtin_amdgcn_mfma_f32_16x16x32_bf16(ap0[kst], bv[t * 2 + kst], o0[t], 0, 0, 0); \
        o1[t] = __builtin_amdgcn_mfma_f32_16x16x32_bf16(ap1[kst], bv[t * 2 + kst], o1[t], 0, 0, 0); \
      }                                                                        \
    }                                                                          \
    __builtin_amdgcn_s_setprio(0);                                             \
    __syncthreads(); /* drains vmcnt (next-tile K DMA) + guards K buffer */    \
  }

__global__ __launch_bounds__(256, 2) void attn(const short* __restrict__ Qp,
                                               const short* __restrict__ Kp,
                                               const short* __restrict__ Vf,
                                               float* __restrict__ out) {
  __shared__ short sK0[8192], sK1[8192];  // 16 KB each, fragment-order
  __shared__ short sP[4 * 16 * PSTR];     // per-wave P region

  int tid = threadIdx.x;
  int lane = tid & 63, w = tid >> 6;
  // XCD chunk-swizzle (bijective, 512 blocks): XCD x owns works [x*64,(x+1)*64)
  int swz = (blockIdx.x & 7) * 64 + (blockIdx.x >> 3);
  int qt = swz & 15; // 16 q-tiles of 128
  int bh = swz >> 4; // 0..31
  int q0 = qt * 128;
  int l15 = lane & 15, l4 = lane >> 4;

  const short* Qbase = Qp + (size_t)bh * S_ * D_;
  const short* Kbase = Kp + (size_t)bh * S_ * D_;
  const short* vfb = Vf + (size_t)bh * S_ * D_ + lane * 8;  // frag-linear V

  // K DMA source address (fragment-order image)
  const short* kg = Kbase + (w * 16 + l15) * D_ + l4 * 8;

  // stage K tile 0 into buffer 0
  {
    short* kl = sK0 + (w * 4) * 512;
    dma16(kg, kl);
    dma16(kg + 32, kl + 512);
    dma16(kg + 64, kl + 1024);
    dma16(kg + 96, kl + 1536);
  }

  // Q B-fragments for two 16-q groups (q = q0 + w*32 + g*16 + l15)
  bf16x8 aq[2][4];
#pragma unroll
  for (int g = 0; g < 2; ++g)
#pragma unroll
    for (int st = 0; st < 4; ++st)
      aq[g][st] = *(const bf16x8*)(Qbase + (q0 + w * 32 + g * 16 + l15) * D_ + l4 * 8 + 32 * st);

  f32x4 o0[8], o1[8];
#pragma unroll
  for (int t = 0; t < 8; ++t) {
    o0[t] = (f32x4){0.f, 0.f, 0.f, 0.f};
    o1[t] = (f32x4){0.f, 0.f, 0.f, 0.f};
  }
  float ls0 = 0.f, ls1 = 0.f;

  const float SC2 = 0.127530637f; // log2(e)/sqrt(128)
  short* pw = sP + w * 16 * PSTR;

  __syncthreads(); // tile 0 K DMA complete

  for (int it = 0; it < S_ / BN; it += 2) {
    ATTN_ITER(sK0, sK1, it);
    ATTN_ITER(sK1, sK0, it + 1);
  }

  // final softmax denominators: per-lane partial sums -> quad reduce
  ls0 += __shfl_xor(ls0, 16);
  ls0 += __shfl_xor(ls0, 32);
  ls1 += __shfl_xor(ls1, 16);
  ls1 += __shfl_xor(ls1, 32);
  float inv0[4], inv1[4];
#pragma unroll
  for (int r = 0; r < 4; ++r) {
    inv0[r] = 1.f / __shfl(ls0, l4 * 4 + r);
    inv1[r] = 1.f / __shfl(ls1, l4 * 4 + r);
  }

  // epilogue: out[b, q, h*128 + dv] fp32
  int bb = bh >> 3, h = bh & 7;
#pragma unroll
  for (int t = 0; t < 8; ++t) {
#pragma unroll
    for (int r = 0; r < 4; ++r) {
      int qA = q0 + w * 32 + l4 * 4 + r;
      int qB = qA + 16;
      out[((size_t)(bb * S_ + qA)) * (H_ * D_) + h * D_ + t * 16 + l15] = o0[t][r] * inv0[r];
      out[((size_t)(bb * S_ + qB)) * (H_ * D_) + h * D_ + t * 16 + l15] = o1[t][r] * inv1[r];
    }
  }
}

extern "C" void kernel_launch(void* const* d_in, const int* in_sizes, int n_in,
                              void* d_out, int out_size, void* d_ws, size_t ws_size,
                              hipStream_t stream) {
  (void)in_sizes; (void)n_in; (void)out_size; (void)ws_size;
  const float* q  = (const float*)d_in[0];
  const float* k  = (const float*)d_in[1];
  const float* v  = (const float*)d_in[2];
  const float* WQ = (const float*)d_in[3];
  const float* bQ = (const float*)d_in[4];
  const float* WK = (const float*)d_in[5];
  const float* bK = (const float*)d_in[6];
  const float* WV = (const float*)d_in[7];
  const float* bV = (const float*)d_in[8];

  const int NX = B_ * S_ * D_;      // 1048576 elems per input tensor
  const int NW = D_ * H_ * D_;      // 131072 per weight
  const int NP = B_ * H_ * S_ * D_; // 8388608 per projected tensor

  short* ws  = (short*)d_ws;
  short* xq  = ws;
  short* xk  = xq + NX;
  short* xv  = xk + NX;
  short* wtq = xv + NX;
  short* wtk = wtq + NW;
  short* wtv = wtk + NW;
  short* Qp  = wtv + NW;
  short* Kp  = Qp + NP;
  short* Vf  = Kp + NP;

  prep<<<3168, 256, 0, stream>>>(q, k, v, xq, xk, xv, WQ, WK, WV, wtq, wtk, wtv);

  proj3<<<1536, 256, 0, stream>>>(xq, xk, xv, wtq, wtk, wtv, bQ, bK, bV, Qp, Kp, Vf);

  attn<<<512, 256, 0, stream>>>(Qp, Kp, Vf, (float*)d_out);
}